// Round 1
// baseline (1943.855 us; speedup 1.0000x reference)
//
#include <hip/hip_runtime.h>

#define TT 8192
#define DD 64
#define BB 2
#define NROWS (BB * TT)  // 16384

// ws layout: m[16384] | l[16384] | invl[16384]  (192 KB)

// Kernel A: m[r] = ||x_r||^2, l[r] = 0, zero out.
__global__ __launch_bounds__(256) void ka_init(const float* __restrict__ x,
                                               float* __restrict__ m,
                                               float* __restrict__ l,
                                               float* __restrict__ out) {
  int r = blockIdx.x * 256 + threadIdx.x;  // 0..16383
  const float4* row = (const float4*)(x + (size_t)r * DD);
  float s0 = 0.f, s1 = 0.f, s2 = 0.f, s3 = 0.f;
#pragma unroll
  for (int q = 0; q < 16; ++q) {
    float4 v = row[q];
    s0 += v.x * v.x;
    s1 += v.y * v.y;
    s2 += v.z * v.z;
    s3 += v.w * v.w;
  }
  m[r] = (s0 + s1) + (s2 + s3);
  l[r] = 0.f;
  // zero output: 1,048,576 floats = 262,144 float4 / 16384 threads = 16 each
  float4* o4 = (float4*)out;
#pragma unroll
  for (int q = 0; q < 16; ++q) o4[q * NROWS + r] = make_float4(0.f, 0.f, 0.f, 0.f);
}

// Kernel B: l[r] += sum_k exp(x_r . x_k - m_r) over this block's k-range.
// One thread per row r; k-row loads are wave-uniform -> scalar loads.
__global__ __launch_bounds__(256) void kb_rowsum(const float* __restrict__ x,
                                                 const float* __restrict__ m,
                                                 float* __restrict__ l) {
  int r = blockIdx.x * 256 + threadIdx.x;
  int b = r >> 13;
  float4 xj[16];
  const float4* rowj = (const float4*)(x + (size_t)r * DD);
#pragma unroll
  for (int q = 0; q < 16; ++q) xj[q] = rowj[q];
  float mj = m[r];
  float lsum = 0.f;
  const int KRANGE = TT / 16;  // k-split = 16
  int k0 = blockIdx.y * KRANGE;
  const float* xb = x + (((size_t)b) << 13) * DD;
  for (int k = k0; k < k0 + KRANGE; ++k) {
    const float4* rowk = (const float4*)(xb + (size_t)k * DD);
    float d0 = 0.f, d1 = 0.f, d2 = 0.f, d3 = 0.f;
#pragma unroll
    for (int q = 0; q < 16; ++q) {
      float4 v = rowk[q];  // uniform address -> s_load, broadcast into v_fma
      d0 += xj[q].x * v.x;
      d1 += xj[q].y * v.y;
      d2 += xj[q].z * v.z;
      d3 += xj[q].w * v.w;
    }
    float dot = (d0 + d1) + (d2 + d3);
    lsum += __expf(dot - mj);
  }
  atomicAdd(&l[r], lsum);
}

// Kernel B2: invl = 1/l
__global__ __launch_bounds__(256) void kb2_inv(const float* __restrict__ l,
                                               float* __restrict__ invl) {
  int r = blockIdx.x * 256 + threadIdx.x;
  invl[r] = 1.0f / l[r];
}

// Kernel C: out_t[b][d][i] += sum_j exp(x_i . x_j - m_j) * invl_j * x_j[d]
// One thread per output column i (owns x_i in VGPRs + acc[64]).
__global__ __launch_bounds__(256) void kc_out(const float* __restrict__ x,
                                              const float* __restrict__ m,
                                              const float* __restrict__ invl,
                                              float* __restrict__ out) {
  int r = blockIdx.x * 256 + threadIdx.x;  // global i-row
  int b = r >> 13;
  int i = r & (TT - 1);
  float4 xi[16];
  const float4* rowi = (const float4*)(x + (size_t)r * DD);
#pragma unroll
  for (int q = 0; q < 16; ++q) xi[q] = rowi[q];
  float4 acc[16];
#pragma unroll
  for (int q = 0; q < 16; ++q) acc[q] = make_float4(0.f, 0.f, 0.f, 0.f);

  const int JRANGE = TT / 8;  // j-split = 8
  int j0 = blockIdx.y * JRANGE;
  const float* xb = x + (((size_t)b) << 13) * DD;
  const float* mb = m + (((size_t)b) << 13);
  const float* ib = invl + (((size_t)b) << 13);

  for (int j = j0; j < j0 + JRANGE; ++j) {
    const float4* rowj = (const float4*)(xb + (size_t)j * DD);
    float4 v[16];
    float d0 = 0.f, d1 = 0.f, d2 = 0.f, d3 = 0.f;
#pragma unroll
    for (int q = 0; q < 16; ++q) {
      v[q] = rowj[q];  // uniform -> scalar regs, reused below without reload
      d0 += xi[q].x * v[q].x;
      d1 += xi[q].y * v[q].y;
      d2 += xi[q].z * v[q].z;
      d3 += xi[q].w * v[q].w;
    }
    float dot = (d0 + d1) + (d2 + d3);
    float w = __expf(dot - mb[j]) * ib[j];
#pragma unroll
    for (int q = 0; q < 16; ++q) {
      acc[q].x += w * v[q].x;
      acc[q].y += w * v[q].y;
      acc[q].z += w * v[q].z;
      acc[q].w += w * v[q].w;
    }
  }

  // out flat index: ((b*64 + d) << 13) + i ; consecutive lanes -> consecutive i
  float* ob = out + ((((size_t)b) * DD) << 13) + i;
#pragma unroll
  for (int q = 0; q < 16; ++q) {
    atomicAdd(ob + (((size_t)(q * 4 + 0)) << 13), acc[q].x);
    atomicAdd(ob + (((size_t)(q * 4 + 1)) << 13), acc[q].y);
    atomicAdd(ob + (((size_t)(q * 4 + 2)) << 13), acc[q].z);
    atomicAdd(ob + (((size_t)(q * 4 + 3)) << 13), acc[q].w);
  }
}

extern "C" void kernel_launch(void* const* d_in, const int* in_sizes, int n_in,
                              void* d_out, int out_size, void* d_ws, size_t ws_size,
                              hipStream_t stream) {
  const float* x = (const float*)d_in[0];
  float* out = (float*)d_out;
  float* m = (float*)d_ws;
  float* l = m + NROWS;
  float* invl = l + NROWS;

  ka_init<<<NROWS / 256, 256, 0, stream>>>(x, m, l, out);
  kb_rowsum<<<dim3(NROWS / 256, 16), 256, 0, stream>>>(x, m, l);
  kb2_inv<<<NROWS / 256, 256, 0, stream>>>(l, invl);
  kc_out<<<dim3(NROWS / 256, 8), 256, 0, stream>>>(x, m, invl, out);
}

// Round 2
// 464.713 us; speedup vs baseline: 4.1829x; 4.1829x over previous
//
#include <hip/hip_runtime.h>

#define TT 8192
#define DD 64
#define BB 2
#define NROWS (BB * TT)  // 16384

typedef __attribute__((ext_vector_type(8))) short bf16x8;
typedef __attribute__((ext_vector_type(4))) float f32x4;

// ws layout: xb bf16[16384*64] (2MB) | xt bf16[2*64*8192] (2MB) | m | l | invl (fp32[16384] each)

__device__ inline unsigned short f2bf(float f) {
  unsigned int u = __float_as_uint(f);
  u += 0x7FFF + ((u >> 16) & 1);  // RNE
  return (unsigned short)(u >> 16);
}
__device__ inline float bf2f(unsigned short h) {
  return __uint_as_float(((unsigned int)h) << 16);
}
__device__ inline unsigned int pk2bf(float lo, float hi) {
  return (unsigned int)f2bf(lo) | ((unsigned int)f2bf(hi) << 16);
}

// ---------- ka: bf16 convert + transpose + m + zero l/out ----------
__global__ __launch_bounds__(256) void ka_init(const float* __restrict__ x,
                                               unsigned short* __restrict__ xb,
                                               unsigned short* __restrict__ xt,
                                               float* __restrict__ m,
                                               float* __restrict__ l,
                                               float* __restrict__ out) {
  int r = blockIdx.x * 256 + threadIdx.x;  // 0..16383
  int b = r >> 13, t = r & (TT - 1);
  unsigned short h[DD];
  float msum = 0.f;
  const float* row = x + (size_t)r * DD;
#pragma unroll
  for (int d = 0; d < DD; ++d) {
    unsigned short hv = f2bf(row[d]);
    h[d] = hv;
    float f = bf2f(hv);
    msum += f * f;
  }
  // write xb row: 8 x 16B
  uint4* xbr = (uint4*)(xb + (size_t)r * DD);
#pragma unroll
  for (int g = 0; g < 8; ++g) {
    uint4 v;
    v.x = (unsigned int)h[g * 8 + 0] | ((unsigned int)h[g * 8 + 1] << 16);
    v.y = (unsigned int)h[g * 8 + 2] | ((unsigned int)h[g * 8 + 3] << 16);
    v.z = (unsigned int)h[g * 8 + 4] | ((unsigned int)h[g * 8 + 5] << 16);
    v.w = (unsigned int)h[g * 8 + 6] | ((unsigned int)h[g * 8 + 7] << 16);
    xbr[g] = v;
  }
  // transposed copy: xt[b][d][t] — per d, the wave's 64 lanes write 128B contiguous
  unsigned short* xtb = xt + (size_t)b * DD * TT + t;
#pragma unroll
  for (int d = 0; d < DD; ++d) xtb[(size_t)d * TT] = h[d];
  m[r] = msum;
  l[r] = 0.f;
  // zero out: 1,048,576 floats = 262,144 float4 / 16384 threads = 16 each
  float4* o4 = (float4*)out;
#pragma unroll
  for (int g = 0; g < 16; ++g) o4[(size_t)g * NROWS + r] = make_float4(0.f, 0.f, 0.f, 0.f);
}

// ---------- kb: l_j = sum_k exp(x_j . x_k - m_j), MFMA ----------
__global__ __launch_bounds__(256) void kb_l(const unsigned short* __restrict__ xb,
                                            const float* __restrict__ m,
                                            float* __restrict__ l) {
  int w = threadIdx.x >> 6, lane = threadIdx.x & 63;
  int c = lane & 15, q = lane >> 4;
  int b = blockIdx.z;
  int jr = b * TT + blockIdx.x * 64 + w * 16;  // global j-tile base row
  bf16x8 a0 = *(const bf16x8*)(xb + (size_t)(jr + c) * DD + q * 8);
  bf16x8 a1 = *(const bf16x8*)(xb + (size_t)(jr + c) * DD + 32 + q * 8);
  float4 mv = *(const float4*)(m + jr + 4 * q);
  float ls0 = 0.f, ls1 = 0.f, ls2 = 0.f, ls3 = 0.f;
  int k0 = b * TT + blockIdx.y * (TT / 8);
  for (int it = 0; it < 32; ++it) {
    int kb_ = k0 + it * 32;
    const unsigned short* p0 = xb + (size_t)(kb_ + c) * DD + q * 8;
    const unsigned short* p1 = xb + (size_t)(kb_ + 16 + c) * DD + q * 8;
    bf16x8 b00 = *(const bf16x8*)(p0);
    bf16x8 b01 = *(const bf16x8*)(p0 + 32);
    bf16x8 b10 = *(const bf16x8*)(p1);
    bf16x8 b11 = *(const bf16x8*)(p1 + 32);
    f32x4 acc0 = {0.f, 0.f, 0.f, 0.f}, acc1 = {0.f, 0.f, 0.f, 0.f};
    acc0 = __builtin_amdgcn_mfma_f32_16x16x32_bf16(a0, b00, acc0, 0, 0, 0);
    acc0 = __builtin_amdgcn_mfma_f32_16x16x32_bf16(a1, b01, acc0, 0, 0, 0);
    acc1 = __builtin_amdgcn_mfma_f32_16x16x32_bf16(a0, b10, acc1, 0, 0, 0);
    acc1 = __builtin_amdgcn_mfma_f32_16x16x32_bf16(a1, b11, acc1, 0, 0, 0);
    ls0 += __expf(acc0[0] - mv.x) + __expf(acc1[0] - mv.x);
    ls1 += __expf(acc0[1] - mv.y) + __expf(acc1[1] - mv.y);
    ls2 += __expf(acc0[2] - mv.z) + __expf(acc1[2] - mv.z);
    ls3 += __expf(acc0[3] - mv.w) + __expf(acc1[3] - mv.w);
  }
#pragma unroll
  for (int mask = 1; mask < 16; mask <<= 1) {
    ls0 += __shfl_xor(ls0, mask, 64);
    ls1 += __shfl_xor(ls1, mask, 64);
    ls2 += __shfl_xor(ls2, mask, 64);
    ls3 += __shfl_xor(ls3, mask, 64);
  }
  if (c == 0) {
    atomicAdd(&l[jr + 4 * q + 0], ls0);
    atomicAdd(&l[jr + 4 * q + 1], ls1);
    atomicAdd(&l[jr + 4 * q + 2], ls2);
    atomicAdd(&l[jr + 4 * q + 3], ls3);
  }
}

__global__ __launch_bounds__(256) void kb2_inv(const float* __restrict__ l,
                                               float* __restrict__ invl) {
  int r = blockIdx.x * 256 + threadIdx.x;
  invl[r] = 1.0f / l[r];
}

// ---------- kc: out[b][d][i] += sum_j exp(x_j.x_i - m_j)*invl_j * x_j[d] ----------
// QK in S'[j][i] orientation so C-layout col(lane&15)=i matches PV A-operand row.
__global__ __launch_bounds__(256) void kc_out(const unsigned short* __restrict__ xb,
                                              const unsigned short* __restrict__ xt,
                                              const float* __restrict__ m,
                                              const float* __restrict__ invl,
                                              float* __restrict__ out) {
  int w = threadIdx.x >> 6, lane = threadIdx.x & 63;
  int c = lane & 15, q = lane >> 4;
  int b = blockIdx.z;
  int i0 = blockIdx.x * 64 + w * 16;  // i-tile base (within batch)
  int ir = b * TT + i0;
  // B_qk (Xi), loop-invariant
  bf16x8 bq0 = *(const bf16x8*)(xb + (size_t)(ir + c) * DD + q * 8);
  bf16x8 bq1 = *(const bf16x8*)(xb + (size_t)(ir + c) * DD + 32 + q * 8);
  f32x4 o0 = {0.f, 0.f, 0.f, 0.f}, o1 = o0, o2 = o0, o3 = o0;
  const unsigned short* xtb = xt + (size_t)b * DD * TT;
  int src0 = c + 32 * (q & 1);
  int src1 = src0 + 16;
  bool useT1 = (q >= 2);
  int jbeg = blockIdx.y * (TT / 8);
  for (int it = 0; it < 32; ++it) {
    int j0c = jbeg + it * 32;      // within batch
    int jr = b * TT + j0c;        // global row
    const unsigned short* pa0 = xb + (size_t)(jr + c) * DD + q * 8;
    const unsigned short* pa1 = xb + (size_t)(jr + 16 + c) * DD + q * 8;
    bf16x8 a00 = *(const bf16x8*)(pa0);
    bf16x8 a01 = *(const bf16x8*)(pa0 + 32);
    bf16x8 a10 = *(const bf16x8*)(pa1);
    bf16x8 a11 = *(const bf16x8*)(pa1 + 32);
    f32x4 s0 = {0.f, 0.f, 0.f, 0.f}, s1 = {0.f, 0.f, 0.f, 0.f};
    s0 = __builtin_amdgcn_mfma_f32_16x16x32_bf16(a00, bq0, s0, 0, 0, 0);
    s0 = __builtin_amdgcn_mfma_f32_16x16x32_bf16(a01, bq1, s0, 0, 0, 0);
    s1 = __builtin_amdgcn_mfma_f32_16x16x32_bf16(a10, bq0, s1, 0, 0, 0);
    s1 = __builtin_amdgcn_mfma_f32_16x16x32_bf16(a11, bq1, s1, 0, 0, 0);
    // weights: row j = jr + T*16 + 4q + r  (C-layout), col i = i0 + c
    float4 m0 = *(const float4*)(m + jr + 4 * q);
    float4 m1 = *(const float4*)(m + jr + 16 + 4 * q);
    float4 v0 = *(const float4*)(invl + jr + 4 * q);
    float4 v1 = *(const float4*)(invl + jr + 16 + 4 * q);
    float w00 = __expf(s0[0] - m0.x) * v0.x;
    float w01 = __expf(s0[1] - m0.y) * v0.y;
    float w02 = __expf(s0[2] - m0.z) * v0.z;
    float w03 = __expf(s0[3] - m0.w) * v0.w;
    float w10 = __expf(s1[0] - m1.x) * v1.x;
    float w11 = __expf(s1[1] - m1.y) * v1.y;
    float w12 = __expf(s1[2] - m1.z) * v1.z;
    float w13 = __expf(s1[3] - m1.w) * v1.w;
    // pack pairs along r: pk[T][p] = (r=2p lo, r=2p+1 hi)
    unsigned int pk00 = pk2bf(w00, w01), pk01 = pk2bf(w02, w03);
    unsigned int pk10 = pk2bf(w10, w11), pk11 = pk2bf(w12, w13);
    // A_pv dword p: p0=(src0,pk[T][0]) p1=(src0,pk[T][1]) p2=(src1,pk[T][0]) p3=(src1,pk[T][1])
    unsigned int g00 = (unsigned int)__shfl((int)pk00, src0, 64);
    unsigned int g01 = (unsigned int)__shfl((int)pk01, src0, 64);
    unsigned int g10 = (unsigned int)__shfl((int)pk10, src0, 64);
    unsigned int g11 = (unsigned int)__shfl((int)pk11, src0, 64);
    unsigned int h00 = (unsigned int)__shfl((int)pk00, src1, 64);
    unsigned int h01 = (unsigned int)__shfl((int)pk01, src1, 64);
    unsigned int h10 = (unsigned int)__shfl((int)pk10, src1, 64);
    unsigned int h11 = (unsigned int)__shfl((int)pk11, src1, 64);
    unsigned int d0 = useT1 ? g10 : g00;
    unsigned int d1 = useT1 ? g11 : g01;
    unsigned int d2 = useT1 ? h10 : h00;
    unsigned int d3 = useT1 ? h11 : h01;
    union { unsigned int u[4]; bf16x8 v; } apv;
    apv.u[0] = d0; apv.u[1] = d1; apv.u[2] = d2; apv.u[3] = d3;
    // B_pv from xt: [k=j][n=d] — 16B contiguous in j at fixed d
    const unsigned short* pb = xtb + (size_t)c * TT + j0c + q * 8;
    bf16x8 bv0 = *(const bf16x8*)(pb);
    bf16x8 bv1 = *(const bf16x8*)(pb + (size_t)16 * TT);
    bf16x8 bv2 = *(const bf16x8*)(pb + (size_t)32 * TT);
    bf16x8 bv3 = *(const bf16x8*)(pb + (size_t)48 * TT);
    o0 = __builtin_amdgcn_mfma_f32_16x16x32_bf16(apv.v, bv0, o0, 0, 0, 0);
    o1 = __builtin_amdgcn_mfma_f32_16x16x32_bf16(apv.v, bv1, o1, 0, 0, 0);
    o2 = __builtin_amdgcn_mfma_f32_16x16x32_bf16(apv.v, bv2, o2, 0, 0, 0);
    o3 = __builtin_amdgcn_mfma_f32_16x16x32_bf16(apv.v, bv3, o3, 0, 0, 0);
  }
  // O C-layout: row i = 4q+r, col d = nt*16 + c. out[b][d][i0+i]
  float* ob = out + (size_t)b * DD * TT;
#pragma unroll
  for (int r = 0; r < 4; ++r) {
    int i = i0 + 4 * q + r;
    atomicAdd(&ob[(size_t)(0 * 16 + c) * TT + i], o0[r]);
    atomicAdd(&ob[(size_t)(1 * 16 + c) * TT + i], o1[r]);
    atomicAdd(&ob[(size_t)(2 * 16 + c) * TT + i], o2[r]);
    atomicAdd(&ob[(size_t)(3 * 16 + c) * TT + i], o3[r]);
  }
}

extern "C" void kernel_launch(void* const* d_in, const int* in_sizes, int n_in,
                              void* d_out, int out_size, void* d_ws, size_t ws_size,
                              hipStream_t stream) {
  const float* x = (const float*)d_in[0];
  float* out = (float*)d_out;
  unsigned short* xb = (unsigned short*)d_ws;
  unsigned short* xt = xb + (size_t)NROWS * DD;
  float* m = (float*)(xt + (size_t)NROWS * DD);
  float* l = m + NROWS;
  float* invl = l + NROWS;

  ka_init<<<NROWS / 256, 256, 0, stream>>>(x, xb, xt, m, l, out);
  kb_l<<<dim3(TT / 64, 8, BB), 256, 0, stream>>>(xb, m, l);
  kb2_inv<<<NROWS / 256, 256, 0, stream>>>(l, invl);
  kc_out<<<dim3(TT / 64, 8, BB), 256, 0, stream>>>(xb, xt, m, invl, out);
}

// Round 3
// 460.082 us; speedup vs baseline: 4.2250x; 1.0101x over previous
//
#include <hip/hip_runtime.h>
#include <hip/hip_bf16.h>

#define TT 8192
#define DD 64
#define BB 2
#define NROWS (BB * TT)  // 16384

typedef __attribute__((ext_vector_type(8))) short bf16x8;
typedef __attribute__((ext_vector_type(4))) float f32x4;

#define MFMA16 __builtin_amdgcn_mfma_f32_16x16x32_bf16

// ws layout: xb bf16[16384*64] (2MB) | xt bf16[2*64*8192] (2MB) | m | l | invl (fp32[16384] each)

__device__ inline unsigned short f2bf(float f) {
  unsigned int u = __float_as_uint(f);
  u += 0x7FFF + ((u >> 16) & 1);  // RNE
  return (unsigned short)(u >> 16);
}
__device__ inline float bf2f(unsigned short h) {
  return __uint_as_float(((unsigned int)h) << 16);
}
__device__ inline unsigned int pk2bf(float lo, float hi) {
  // hw v_cvt_pk_bf16_f32 on gfx950 via HIP intrinsic; lo -> low 16 bits
  __hip_bfloat162 h = __float22bfloat162_rn(float2{lo, hi});
  union { __hip_bfloat162 h; unsigned int u; } cv;
  cv.h = h;
  return cv.u;
}

// ---------- ka: bf16 convert + transpose + m. 4 threads per row. ----------
__global__ __launch_bounds__(256) void ka_init(const float* __restrict__ x,
                                               unsigned short* __restrict__ xb,
                                               unsigned short* __restrict__ xt,
                                               float* __restrict__ m) {
  int tid = blockIdx.x * 256 + threadIdx.x;  // 0..65535
  int r = tid >> 2, part = tid & 3;          // row, 16-d slice
  int b = r >> 13, t = r & (TT - 1);
  const float4* px = (const float4*)(x + (size_t)r * DD + part * 16);
  unsigned short h[16];
  float msum = 0.f;
#pragma unroll
  for (int g = 0; g < 4; ++g) {
    float4 v = px[g];
    unsigned short h0 = f2bf(v.x), h1 = f2bf(v.y), h2 = f2bf(v.z), h3 = f2bf(v.w);
    h[g * 4 + 0] = h0; h[g * 4 + 1] = h1; h[g * 4 + 2] = h2; h[g * 4 + 3] = h3;
    float f0 = bf2f(h0), f1 = bf2f(h1), f2 = bf2f(h2), f3 = bf2f(h3);
    msum += f0 * f0 + f1 * f1 + f2 * f2 + f3 * f3;
  }
  uint4* xbr = (uint4*)(xb + (size_t)r * DD + part * 16);
#pragma unroll
  for (int g = 0; g < 2; ++g) {
    uint4 v;
    v.x = (unsigned int)h[g * 8 + 0] | ((unsigned int)h[g * 8 + 1] << 16);
    v.y = (unsigned int)h[g * 8 + 2] | ((unsigned int)h[g * 8 + 3] << 16);
    v.z = (unsigned int)h[g * 8 + 4] | ((unsigned int)h[g * 8 + 5] << 16);
    v.w = (unsigned int)h[g * 8 + 6] | ((unsigned int)h[g * 8 + 7] << 16);
    xbr[g] = v;
  }
  unsigned short* xtb = xt + (size_t)b * DD * TT + t;
#pragma unroll
  for (int k = 0; k < 16; ++k) xtb[(size_t)(part * 16 + k) * TT] = h[k];
  msum += __shfl_xor(msum, 1, 64);
  msum += __shfl_xor(msum, 2, 64);
  if (part == 0) m[r] = msum;
}

// ---------- kb: l_j = sum_k exp(x_j . x_k - m_j), MFMA + 1-ahead prefetch ----------
__global__ __launch_bounds__(256) void kb_l(const unsigned short* __restrict__ xb,
                                            const float* __restrict__ m,
                                            float* __restrict__ l) {
  int w = threadIdx.x >> 6, lane = threadIdx.x & 63;
  int c = lane & 15, q = lane >> 4;
  int b = blockIdx.z;
  int jr = b * TT + blockIdx.x * 64 + w * 16;
  bf16x8 a0 = *(const bf16x8*)(xb + (size_t)(jr + c) * DD + q * 8);
  bf16x8 a1 = *(const bf16x8*)(xb + (size_t)(jr + c) * DD + 32 + q * 8);
  float4 mv = *(const float4*)(m + jr + 4 * q);
  float ls0 = 0.f, ls1 = 0.f, ls2 = 0.f, ls3 = 0.f;
  int k0 = b * TT + blockIdx.y * (TT / 8);

  bf16x8 B[2][4];
  auto fetchB = [&](int buf, int kb_) {
    const unsigned short* p0 = xb + (size_t)(kb_ + c) * DD + q * 8;
    const unsigned short* p1 = xb + (size_t)(kb_ + 16 + c) * DD + q * 8;
    B[buf][0] = *(const bf16x8*)(p0);
    B[buf][1] = *(const bf16x8*)(p0 + 32);
    B[buf][2] = *(const bf16x8*)(p1);
    B[buf][3] = *(const bf16x8*)(p1 + 32);
  };
  fetchB(0, k0);
#pragma unroll 2
  for (int it = 0; it < 32; ++it) {
    int bu = it & 1;
    if (it < 31) fetchB(bu ^ 1, k0 + (it + 1) * 32);
    f32x4 acc0 = {0.f, 0.f, 0.f, 0.f}, acc1 = {0.f, 0.f, 0.f, 0.f};
    acc0 = MFMA16(a0, B[bu][0], acc0, 0, 0, 0);
    acc0 = MFMA16(a1, B[bu][1], acc0, 0, 0, 0);
    acc1 = MFMA16(a0, B[bu][2], acc1, 0, 0, 0);
    acc1 = MFMA16(a1, B[bu][3], acc1, 0, 0, 0);
    ls0 += __expf(acc0[0] - mv.x) + __expf(acc1[0] - mv.x);
    ls1 += __expf(acc0[1] - mv.y) + __expf(acc1[1] - mv.y);
    ls2 += __expf(acc0[2] - mv.z) + __expf(acc1[2] - mv.z);
    ls3 += __expf(acc0[3] - mv.w) + __expf(acc1[3] - mv.w);
  }
#pragma unroll
  for (int mask = 1; mask < 16; mask <<= 1) {
    ls0 += __shfl_xor(ls0, mask, 64);
    ls1 += __shfl_xor(ls1, mask, 64);
    ls2 += __shfl_xor(ls2, mask, 64);
    ls3 += __shfl_xor(ls3, mask, 64);
  }
  if (c == 0) {
    atomicAdd(&l[jr + 4 * q + 0], ls0);
    atomicAdd(&l[jr + 4 * q + 1], ls1);
    atomicAdd(&l[jr + 4 * q + 2], ls2);
    atomicAdd(&l[jr + 4 * q + 3], ls3);
  }
}

__global__ __launch_bounds__(256) void kb2_inv(const float* __restrict__ l,
                                               float* __restrict__ invl) {
  int r = blockIdx.x * 256 + threadIdx.x;
  invl[r] = 1.0f / l[r];
}

// ---------- kc: out[b][d][i] += sum_j exp(x_j.x_i - m_j)*invl_j * x_j[d] ----------
// QK in S'[j][i] orientation; C-layout col (lane&15) = i matches PV A-operand row.
// Software-pipelined: A-frags prefetched 1 iter ahead; per-iter loads issued
// before the prefetch so no wait drains the pipeline (vmcnt(N>0) style).
__global__ __launch_bounds__(256) void kc_out(const unsigned short* __restrict__ xb,
                                              const unsigned short* __restrict__ xt,
                                              const float* __restrict__ m,
                                              const float* __restrict__ invl,
                                              float* __restrict__ out) {
  int w = threadIdx.x >> 6, lane = threadIdx.x & 63;
  int c = lane & 15, q = lane >> 4;
  int b = blockIdx.z;
  int i0 = blockIdx.x * 64 + w * 16;
  int ir = b * TT + i0;
  bf16x8 bq0 = *(const bf16x8*)(xb + (size_t)(ir + c) * DD + q * 8);
  bf16x8 bq1 = *(const bf16x8*)(xb + (size_t)(ir + c) * DD + 32 + q * 8);
  f32x4 o0 = {0.f, 0.f, 0.f, 0.f}, o1 = o0, o2 = o0, o3 = o0;
  const unsigned short* xtb = xt + (size_t)b * DD * TT;
  int src0 = c + 32 * (q & 1);
  int src1 = src0 + 16;
  bool useT1 = (q >= 2);
  const int NITER = 64;  // y-split 4 -> 2048 j per block, 32 per iter
  int jbeg = blockIdx.y * (TT / 4);

  bf16x8 A[2][4];
  auto fetchA = [&](int buf, int j0c) {
    int jr = b * TT + j0c;
    const unsigned short* pa0 = xb + (size_t)(jr + c) * DD + q * 8;
    const unsigned short* pa1 = xb + (size_t)(jr + 16 + c) * DD + q * 8;
    A[buf][0] = *(const bf16x8*)(pa0);
    A[buf][1] = *(const bf16x8*)(pa0 + 32);
    A[buf][2] = *(const bf16x8*)(pa1);
    A[buf][3] = *(const bf16x8*)(pa1 + 32);
  };
  fetchA(0, jbeg);

#pragma unroll 2
  for (int it = 0; it < NITER; ++it) {
    int bu = it & 1;
    int j0c = jbeg + it * 32;
    int jr = b * TT + j0c;
    // current-iter small loads first (waits on these leave A-prefetch in flight)
    float4 m0 = *(const float4*)(m + jr + 4 * q);
    float4 m1 = *(const float4*)(m + jr + 16 + 4 * q);
    float4 v0 = *(const float4*)(invl + jr + 4 * q);
    float4 v1 = *(const float4*)(invl + jr + 16 + 4 * q);
    // PV B-frags for current iter (needed last -> latency covered by QK+exp+shfl)
    const unsigned short* pb = xtb + (size_t)c * TT + j0c + q * 8;
    bf16x8 bv0 = *(const bf16x8*)(pb);
    bf16x8 bv1 = *(const bf16x8*)(pb + (size_t)16 * TT);
    bf16x8 bv2 = *(const bf16x8*)(pb + (size_t)32 * TT);
    bf16x8 bv3 = *(const bf16x8*)(pb + (size_t)48 * TT);
    // prefetch next iter's A-frags
    if (it < NITER - 1) fetchA(bu ^ 1, j0c + 32);

    f32x4 s0 = {0.f, 0.f, 0.f, 0.f}, s1 = {0.f, 0.f, 0.f, 0.f};
    s0 = MFMA16(A[bu][0], bq0, s0, 0, 0, 0);
    s0 = MFMA16(A[bu][1], bq1, s0, 0, 0, 0);
    s1 = MFMA16(A[bu][2], bq0, s1, 0, 0, 0);
    s1 = MFMA16(A[bu][3], bq1, s1, 0, 0, 0);

    float w00 = __expf(s0[0] - m0.x) * v0.x;
    float w01 = __expf(s0[1] - m0.y) * v0.y;
    float w02 = __expf(s0[2] - m0.z) * v0.z;
    float w03 = __expf(s0[3] - m0.w) * v0.w;
    float w10 = __expf(s1[0] - m1.x) * v1.x;
    float w11 = __expf(s1[1] - m1.y) * v1.y;
    float w12 = __expf(s1[2] - m1.z) * v1.z;
    float w13 = __expf(s1[3] - m1.w) * v1.w;

    unsigned int pk00 = pk2bf(w00, w01), pk01 = pk2bf(w02, w03);
    unsigned int pk10 = pk2bf(w10, w11), pk11 = pk2bf(w12, w13);

    unsigned int g00 = (unsigned int)__shfl((int)pk00, src0, 64);
    unsigned int g01 = (unsigned int)__shfl((int)pk01, src0, 64);
    unsigned int g10 = (unsigned int)__shfl((int)pk10, src0, 64);
    unsigned int g11 = (unsigned int)__shfl((int)pk11, src0, 64);
    unsigned int h00 = (unsigned int)__shfl((int)pk00, src1, 64);
    unsigned int h01 = (unsigned int)__shfl((int)pk01, src1, 64);
    unsigned int h10 = (unsigned int)__shfl((int)pk10, src1, 64);
    unsigned int h11 = (unsigned int)__shfl((int)pk11, src1, 64);
    union { unsigned int u[4]; bf16x8 v; } apv;
    apv.u[0] = useT1 ? g10 : g00;
    apv.u[1] = useT1 ? g11 : g01;
    apv.u[2] = useT1 ? h10 : h00;
    apv.u[3] = useT1 ? h11 : h01;

    o0 = MFMA16(apv.v, bv0, o0, 0, 0, 0);
    o1 = MFMA16(apv.v, bv1, o1, 0, 0, 0);
    o2 = MFMA16(apv.v, bv2, o2, 0, 0, 0);
    o3 = MFMA16(apv.v, bv3, o3, 0, 0, 0);
  }

  float* ob = out + (size_t)b * DD * TT;
#pragma unroll
  for (int r = 0; r < 4; ++r) {
    int i = i0 + 4 * q + r;
    atomicAdd(&ob[(size_t)(0 * 16 + c) * TT + i], o0[r]);
    atomicAdd(&ob[(size_t)(1 * 16 + c) * TT + i], o1[r]);
    atomicAdd(&ob[(size_t)(2 * 16 + c) * TT + i], o2[r]);
    atomicAdd(&ob[(size_t)(3 * 16 + c) * TT + i], o3[r]);
  }
}

extern "C" void kernel_launch(void* const* d_in, const int* in_sizes, int n_in,
                              void* d_out, int out_size, void* d_ws, size_t ws_size,
                              hipStream_t stream) {
  const float* x = (const float*)d_in[0];
  float* out = (float*)d_out;
  unsigned short* xb = (unsigned short*)d_ws;
  unsigned short* xt = xb + (size_t)NROWS * DD;
  float* m = (float*)(xt + (size_t)NROWS * DD);
  float* l = m + NROWS;
  float* invl = l + NROWS;

  hipMemsetAsync(out, 0, (size_t)out_size * sizeof(float), stream);
  hipMemsetAsync(l, 0, NROWS * sizeof(float), stream);
  ka_init<<<NROWS * 4 / 256, 256, 0, stream>>>(x, xb, xt, m);
  kb_l<<<dim3(TT / 64, 8, BB), 256, 0, stream>>>(xb, m, l);
  kb2_inv<<<NROWS / 256, 256, 0, stream>>>(l, invl);
  kc_out<<<dim3(TT / 64, 4, BB), 256, 0, stream>>>(xb, xt, m, invl, out);
}

// Round 4
// 216.816 us; speedup vs baseline: 8.9655x; 2.1220x over previous
//
#include <hip/hip_runtime.h>
#include <hip/hip_bf16.h>

#define TT 8192
#define DD 64
#define BB 2
#define NROWS (BB * TT)  // 16384

typedef __attribute__((ext_vector_type(8))) short bf16x8;
typedef __attribute__((ext_vector_type(4))) float f32x4;

#define MFMA16 __builtin_amdgcn_mfma_f32_16x16x32_bf16

typedef __attribute__((address_space(1))) const unsigned int gu32;
typedef __attribute__((address_space(3))) unsigned int lu32;

// async global->LDS, 16B per lane; LDS dest = uniform base + lane*16
__device__ inline void gld_lds16(const unsigned short* g, unsigned short* l) {
  __builtin_amdgcn_global_load_lds((gu32*)g, (lu32*)l, 16, 0, 0);
}

// ws layout: xb bf16[16384*64] (2MB) | xt bf16[2*64*8192] (2MB) | m | l | invl (fp32[16384] each)

__device__ inline unsigned short f2bf(float f) {
  unsigned int u = __float_as_uint(f);
  u += 0x7FFF + ((u >> 16) & 1);  // RNE
  return (unsigned short)(u >> 16);
}
__device__ inline float bf2f(unsigned short h) {
  return __uint_as_float(((unsigned int)h) << 16);
}
__device__ inline unsigned int pk2bf(float lo, float hi) {
  __hip_bfloat162 h = __float22bfloat162_rn(float2{lo, hi});
  union { __hip_bfloat162 h; unsigned int u; } cv;
  cv.h = h;
  return cv.u;
}

// ---------- ka: bf16 convert + m + xb + LDS-transposed xt ----------
// 64 rows per block; 4 threads per row (16 d each).
__global__ __launch_bounds__(256) void ka_init(const float* __restrict__ x,
                                               unsigned short* __restrict__ xb,
                                               unsigned short* __restrict__ xt,
                                               float* __restrict__ m) {
  __shared__ __align__(16) unsigned short tile[64 * 72];  // row stride 72 shorts (144B, 16B-mult)
  int t = threadIdx.x;
  int r0 = blockIdx.x * 64;
  int rloc = t >> 2, part = t & 3;
  int r = r0 + rloc;
  const float4* px = (const float4*)(x + (size_t)r * DD + part * 16);
  unsigned short h[16];
  float msum = 0.f;
#pragma unroll
  for (int g = 0; g < 4; ++g) {
    float4 v = px[g];
    unsigned short h0 = f2bf(v.x), h1 = f2bf(v.y), h2 = f2bf(v.z), h3 = f2bf(v.w);
    h[g * 4 + 0] = h0; h[g * 4 + 1] = h1; h[g * 4 + 2] = h2; h[g * 4 + 3] = h3;
    float f0 = bf2f(h0), f1 = bf2f(h1), f2 = bf2f(h2), f3 = bf2f(h3);
    msum += f0 * f0 + f1 * f1 + f2 * f2 + f3 * f3;
  }
  uint4* xbr = (uint4*)(xb + (size_t)r * DD + part * 16);
#pragma unroll
  for (int g = 0; g < 2; ++g) {
    uint4 v;
    v.x = (unsigned int)h[g * 8 + 0] | ((unsigned int)h[g * 8 + 1] << 16);
    v.y = (unsigned int)h[g * 8 + 2] | ((unsigned int)h[g * 8 + 3] << 16);
    v.z = (unsigned int)h[g * 8 + 4] | ((unsigned int)h[g * 8 + 5] << 16);
    v.w = (unsigned int)h[g * 8 + 6] | ((unsigned int)h[g * 8 + 7] << 16);
    xbr[g] = v;
  }
#pragma unroll
  for (int k = 0; k < 16; ++k) tile[(part * 16 + k) * 72 + rloc] = h[k];
  msum += __shfl_xor(msum, 1, 64);
  msum += __shfl_xor(msum, 2, 64);
  if (part == 0) m[r] = msum;
  __syncthreads();
  // write xt[b][d][t]: thread -> (d = t>>2, 32B seg = t&3), coalesced in 64B groups
  int d = t >> 2, seg = t & 3;
  int b = r0 >> 13;
  int tcol = (r0 & (TT - 1)) + seg * 16;
  uint4 v0 = *(uint4*)(tile + d * 72 + seg * 16);
  uint4 v1 = *(uint4*)(tile + d * 72 + seg * 16 + 8);
  uint4* dst = (uint4*)(xt + ((size_t)b * DD + d) * TT + tcol);
  dst[0] = v0;
  dst[1] = v1;
}

// ---------- kb: l_j = sum_k exp(x_j . x_k - m_j) ----------
// block = 4 waves x 32 j-rows; k-tiles (32x64) staged in LDS, XOR-swizzled.
__global__ __launch_bounds__(256) void kb_l(const unsigned short* __restrict__ xb,
                                            const float* __restrict__ m,
                                            float* __restrict__ l) {
  __shared__ __align__(16) unsigned short kbuf[2][2048];  // 2 x 4KB
  int w = threadIdx.x >> 6, lane = threadIdx.x & 63;
  int c = lane & 15, q = lane >> 4;
  int b = blockIdx.z;
  int j0 = b * TT + blockIdx.x * 128 + w * 32;
  bf16x8 a0[2], a1[2];
  f32x4 mv[2];
#pragma unroll
  for (int u = 0; u < 2; ++u) {
    const unsigned short* pr = xb + (size_t)(j0 + u * 16 + c) * DD + q * 8;
    a0[u] = *(const bf16x8*)pr;
    a1[u] = *(const bf16x8*)(pr + 32);
    mv[u] = *(const f32x4*)(m + j0 + u * 16 + 4 * q);
  }
  float ls[2][4];
#pragma unroll
  for (int u = 0; u < 2; ++u)
#pragma unroll
    for (int e = 0; e < 4; ++e) ls[u][e] = 0.f;

  // staging: wave w -> rows 8w..8w+7; lane l -> row 8w+(l>>3), chunk (l&7)^((l>>3)&7)
  int arow = 8 * w + (lane >> 3);
  int aqg = (lane & 7) ^ ((lane >> 3) & 7);
  const unsigned short* xbb = xb + (size_t)(b * TT) * DD;
  int ktbase = blockIdx.y * (TT / 8);

  {
    gld_lds16(xbb + (size_t)(ktbase + arow) * DD + aqg * 8, &kbuf[0][w * 512]);
  }
  __syncthreads();
  const int NITER = (TT / 8) / 32;  // 32
  int s1o = (q ^ (c & 7)) * 8, s2o = ((q | 4) ^ (c & 7)) * 8;
  for (int it = 0; it < NITER; ++it) {
    int cur = it & 1;
    if (it + 1 < NITER)
      gld_lds16(xbb + (size_t)(ktbase + (it + 1) * 32 + arow) * DD + aqg * 8,
                &kbuf[cur ^ 1][w * 512]);
    const unsigned short* kp = &kbuf[cur][0];
    bf16x8 b00 = *(const bf16x8*)(kp + c * 64 + s1o);
    bf16x8 b01 = *(const bf16x8*)(kp + c * 64 + s2o);
    bf16x8 b10 = *(const bf16x8*)(kp + (c + 16) * 64 + s1o);
    bf16x8 b11 = *(const bf16x8*)(kp + (c + 16) * 64 + s2o);
#pragma unroll
    for (int u = 0; u < 2; ++u) {
      f32x4 acc0 = {0.f, 0.f, 0.f, 0.f}, acc1 = {0.f, 0.f, 0.f, 0.f};
      acc0 = MFMA16(a0[u], b00, acc0, 0, 0, 0);
      acc0 = MFMA16(a1[u], b01, acc0, 0, 0, 0);
      acc1 = MFMA16(a0[u], b10, acc1, 0, 0, 0);
      acc1 = MFMA16(a1[u], b11, acc1, 0, 0, 0);
#pragma unroll
      for (int e = 0; e < 4; ++e)
        ls[u][e] += __expf(acc0[e] - mv[u][e]) + __expf(acc1[e] - mv[u][e]);
    }
    __syncthreads();
  }
#pragma unroll
  for (int u = 0; u < 2; ++u)
#pragma unroll
    for (int e = 0; e < 4; ++e) {
      float v = ls[u][e];
#pragma unroll
      for (int mask = 1; mask < 16; mask <<= 1) v += __shfl_xor(v, mask, 64);
      if (c == 0) atomicAdd(&l[j0 + u * 16 + 4 * q + e], v);
    }
}

__global__ __launch_bounds__(256) void kb2_inv(const float* __restrict__ l,
                                               float* __restrict__ invl) {
  int r = blockIdx.x * 256 + threadIdx.x;
  invl[r] = 1.0f / l[r];
}

// ---------- kc: out[b][d][i] += sum_j exp(x_j.x_i - m_j)*invl_j * x_j[d] ----------
// block = 4 waves x 32 i's (2 subtiles of 16); j-tiles (A: 32x64 rows, V: xt 64x32)
// staged in double-buffered swizzled LDS via global_load_lds.
__global__ __launch_bounds__(256) void kc_out(const unsigned short* __restrict__ xb,
                                              const unsigned short* __restrict__ xt,
                                              const float* __restrict__ m,
                                              const float* __restrict__ invl,
                                              float* __restrict__ out) {
  __shared__ __align__(16) unsigned short abuf[2][2048];
  __shared__ __align__(16) unsigned short vbuf[2][2048];
  int w = threadIdx.x >> 6, lane = threadIdx.x & 63;
  int c = lane & 15, q = lane >> 4;
  int b = blockIdx.z;
  int ib0 = blockIdx.x * 128;
  bf16x8 bq0[2], bq1[2];
#pragma unroll
  for (int u = 0; u < 2; ++u) {
    const unsigned short* pr =
        xb + (size_t)(b * TT + ib0 + u * 64 + w * 16 + c) * DD + q * 8;
    bq0[u] = *(const bf16x8*)pr;
    bq1[u] = *(const bf16x8*)(pr + 32);
  }
  f32x4 o[2][4];
#pragma unroll
  for (int u = 0; u < 2; ++u)
#pragma unroll
    for (int t = 0; t < 4; ++t) o[u][t] = (f32x4){0.f, 0.f, 0.f, 0.f};

  int src0 = c + 32 * (q & 1);
  int src1 = src0 + 16;
  bool useT1 = (q >= 2);

  // staging constants
  int arow = 8 * w + (lane >> 3);
  int aqg = (lane & 7) ^ ((lane >> 3) & 7);
  int vd = 16 * w + (lane >> 2);
  int vg = (lane & 3) ^ ((lane >> 2) & 3) ^ ((lane >> 4) & 3);
  const unsigned short* xbb = xb + (size_t)(b * TT) * DD;
  const unsigned short* xtb = xt + (size_t)b * DD * TT;
  int jbeg = blockIdx.y * (TT / 4);

  {
    gld_lds16(xbb + (size_t)(jbeg + arow) * DD + aqg * 8, &abuf[0][w * 512]);
    gld_lds16(xtb + (size_t)vd * TT + jbeg + vg * 8, &vbuf[0][w * 512]);
  }
  __syncthreads();

  int swc = (c & 3) ^ ((c >> 2) & 3);
  int s1o = (q ^ (c & 7)) * 8, s2o = ((q | 4) ^ (c & 7)) * 8;
  int vo = (q ^ swc) * 8;
  const int NITER = (TT / 4) / 32;  // 64
  for (int it = 0; it < NITER; ++it) {
    int cur = it & 1;
    int jt = jbeg + it * 32;
    if (it + 1 < NITER) {
      gld_lds16(xbb + (size_t)(jt + 32 + arow) * DD + aqg * 8, &abuf[cur ^ 1][w * 512]);
      gld_lds16(xtb + (size_t)vd * TT + jt + 32 + vg * 8, &vbuf[cur ^ 1][w * 512]);
    }
    int jr = b * TT + jt;
    f32x4 m0 = *(const f32x4*)(m + jr + 4 * q);
    f32x4 m1 = *(const f32x4*)(m + jr + 16 + 4 * q);
    f32x4 v0 = *(const f32x4*)(invl + jr + 4 * q);
    f32x4 v1 = *(const f32x4*)(invl + jr + 16 + 4 * q);
    const unsigned short* ab = &abuf[cur][0];
    const unsigned short* vb = &vbuf[cur][0];
    bf16x8 a00 = *(const bf16x8*)(ab + c * 64 + s1o);
    bf16x8 a01 = *(const bf16x8*)(ab + c * 64 + s2o);
    bf16x8 a10 = *(const bf16x8*)(ab + (c + 16) * 64 + s1o);
    bf16x8 a11 = *(const bf16x8*)(ab + (c + 16) * 64 + s2o);
    bf16x8 bv0 = *(const bf16x8*)(vb + (c) * 32 + vo);
    bf16x8 bv1 = *(const bf16x8*)(vb + (c + 16) * 32 + vo);
    bf16x8 bv2 = *(const bf16x8*)(vb + (c + 32) * 32 + vo);
    bf16x8 bv3 = *(const bf16x8*)(vb + (c + 48) * 32 + vo);
#pragma unroll
    for (int u = 0; u < 2; ++u) {
      f32x4 s0 = {0.f, 0.f, 0.f, 0.f}, s1 = {0.f, 0.f, 0.f, 0.f};
      s0 = MFMA16(a00, bq0[u], s0, 0, 0, 0);
      s0 = MFMA16(a01, bq1[u], s0, 0, 0, 0);
      s1 = MFMA16(a10, bq0[u], s1, 0, 0, 0);
      s1 = MFMA16(a11, bq1[u], s1, 0, 0, 0);
      float w00 = __expf(s0[0] - m0[0]) * v0[0];
      float w01 = __expf(s0[1] - m0[1]) * v0[1];
      float w02 = __expf(s0[2] - m0[2]) * v0[2];
      float w03 = __expf(s0[3] - m0[3]) * v0[3];
      float w10 = __expf(s1[0] - m1[0]) * v1[0];
      float w11 = __expf(s1[1] - m1[1]) * v1[1];
      float w12 = __expf(s1[2] - m1[2]) * v1[2];
      float w13 = __expf(s1[3] - m1[3]) * v1[3];
      unsigned int pk00 = pk2bf(w00, w01), pk01 = pk2bf(w02, w03);
      unsigned int pk10 = pk2bf(w10, w11), pk11 = pk2bf(w12, w13);
      unsigned int g00 = (unsigned int)__shfl((int)pk00, src0, 64);
      unsigned int g01 = (unsigned int)__shfl((int)pk01, src0, 64);
      unsigned int g10 = (unsigned int)__shfl((int)pk10, src0, 64);
      unsigned int g11 = (unsigned int)__shfl((int)pk11, src0, 64);
      unsigned int h00 = (unsigned int)__shfl((int)pk00, src1, 64);
      unsigned int h01 = (unsigned int)__shfl((int)pk01, src1, 64);
      unsigned int h10 = (unsigned int)__shfl((int)pk10, src1, 64);
      unsigned int h11 = (unsigned int)__shfl((int)pk11, src1, 64);
      union { unsigned int u[4]; bf16x8 v; } apv;
      apv.u[0] = useT1 ? g10 : g00;
      apv.u[1] = useT1 ? g11 : g01;
      apv.u[2] = useT1 ? h10 : h00;
      apv.u[3] = useT1 ? h11 : h01;
      o[u][0] = MFMA16(apv.v, bv0, o[u][0], 0, 0, 0);
      o[u][1] = MFMA16(apv.v, bv1, o[u][1], 0, 0, 0);
      o[u][2] = MFMA16(apv.v, bv2, o[u][2], 0, 0, 0);
      o[u][3] = MFMA16(apv.v, bv3, o[u][3], 0, 0, 0);
    }
    __syncthreads();
  }

  float* ob = out + (size_t)b * DD * TT;
#pragma unroll
  for (int u = 0; u < 2; ++u) {
    int i = ib0 + u * 64 + w * 16 + 4 * q;
#pragma unroll
    for (int r = 0; r < 4; ++r) {
      atomicAdd(&ob[(size_t)(0 + c) * TT + i + r], o[u][0][r]);
      atomicAdd(&ob[(size_t)(16 + c) * TT + i + r], o[u][1][r]);
      atomicAdd(&ob[(size_t)(32 + c) * TT + i + r], o[u][2][r]);
      atomicAdd(&ob[(size_t)(48 + c) * TT + i + r], o[u][3][r]);
    }
  }
}

extern "C" void kernel_launch(void* const* d_in, const int* in_sizes, int n_in,
                              void* d_out, int out_size, void* d_ws, size_t ws_size,
                              hipStream_t stream) {
  const float* x = (const float*)d_in[0];
  float* out = (float*)d_out;
  unsigned short* xb = (unsigned short*)d_ws;
  unsigned short* xt = xb + (size_t)NROWS * DD;
  float* m = (float*)(xt + (size_t)NROWS * DD);
  float* l = m + NROWS;
  float* invl = l + NROWS;

  hipMemsetAsync(out, 0, (size_t)out_size * sizeof(float), stream);
  hipMemsetAsync(l, 0, NROWS * sizeof(float), stream);
  ka_init<<<NROWS / 64, 256, 0, stream>>>(x, xb, xt, m);
  kb_l<<<dim3(TT / 128, 8, BB), 256, 0, stream>>>(xb, m, l);
  kb2_inv<<<NROWS / 256, 256, 0, stream>>>(l, invl);
  kc_out<<<dim3(TT / 128, 4, BB), 256, 0, stream>>>(xb, xt, m, invl, out);
}

// Round 6
// 186.175 us; speedup vs baseline: 10.4410x; 1.1646x over previous
//
#include <hip/hip_runtime.h>
#include <hip/hip_bf16.h>

#define TT 8192
#define DD 64
#define BB 2
#define NROWS (BB * TT)  // 16384

typedef __attribute__((ext_vector_type(8))) short bf16x8;
typedef __attribute__((ext_vector_type(4))) float f32x4;

#define MFMA16 __builtin_amdgcn_mfma_f32_16x16x32_bf16

typedef __attribute__((address_space(1))) const unsigned int gu32;
typedef __attribute__((address_space(3))) unsigned int lu32;

// async global->LDS, 16B per lane; LDS dest = wave-uniform base + lane*16
__device__ inline void gld_lds16(const unsigned short* g, unsigned short* l) {
  __builtin_amdgcn_global_load_lds((gu32*)g, (lu32*)l, 16, 0, 0);
}

// ws layout: xb bf16[16384*64] (2MB) | xt bf16[2*64*8192] (2MB) | m fp32[16384] | mm fp32[16384]

__device__ inline unsigned short f2bf(float f) {
  unsigned int u = __float_as_uint(f);
  u += 0x7FFF + ((u >> 16) & 1);  // RNE
  return (unsigned short)(u >> 16);
}
__device__ inline float bf2f(unsigned short h) {
  return __uint_as_float(((unsigned int)h) << 16);
}
__device__ inline unsigned int pk2bf(float lo, float hi) {
  __hip_bfloat162 h = __float22bfloat162_rn(float2{lo, hi});
  union { __hip_bfloat162 h; unsigned int u; } cv;
  cv.h = h;
  return cv.u;
}

// ---------- ka: bf16 convert + m + xb + LDS-transposed xt ----------
__global__ __launch_bounds__(256) void ka_init(const float* __restrict__ x,
                                               unsigned short* __restrict__ xb,
                                               unsigned short* __restrict__ xt,
                                               float* __restrict__ m) {
  __shared__ __align__(16) unsigned short tile[64 * 72];
  int t = threadIdx.x;
  int r0 = blockIdx.x * 64;
  int rloc = t >> 2, part = t & 3;
  int r = r0 + rloc;
  const float4* px = (const float4*)(x + (size_t)r * DD + part * 16);
  unsigned short h[16];
  float msum = 0.f;
#pragma unroll
  for (int g = 0; g < 4; ++g) {
    float4 v = px[g];
    unsigned short h0 = f2bf(v.x), h1 = f2bf(v.y), h2 = f2bf(v.z), h3 = f2bf(v.w);
    h[g * 4 + 0] = h0; h[g * 4 + 1] = h1; h[g * 4 + 2] = h2; h[g * 4 + 3] = h3;
    float f0 = bf2f(h0), f1 = bf2f(h1), f2 = bf2f(h2), f3 = bf2f(h3);
    msum += f0 * f0 + f1 * f1 + f2 * f2 + f3 * f3;
  }
  uint4* xbr = (uint4*)(xb + (size_t)r * DD + part * 16);
#pragma unroll
  for (int g = 0; g < 2; ++g) {
    uint4 v;
    v.x = (unsigned int)h[g * 8 + 0] | ((unsigned int)h[g * 8 + 1] << 16);
    v.y = (unsigned int)h[g * 8 + 2] | ((unsigned int)h[g * 8 + 3] << 16);
    v.z = (unsigned int)h[g * 8 + 4] | ((unsigned int)h[g * 8 + 5] << 16);
    v.w = (unsigned int)h[g * 8 + 6] | ((unsigned int)h[g * 8 + 7] << 16);
    xbr[g] = v;
  }
#pragma unroll
  for (int k = 0; k < 16; ++k) tile[(part * 16 + k) * 72 + rloc] = h[k];
  msum += __shfl_xor(msum, 1, 64);
  msum += __shfl_xor(msum, 2, 64);
  if (part == 0) m[r] = msum;
  __syncthreads();
  int d = t >> 2, seg = t & 3;
  int b = r0 >> 13;
  int tcol = (r0 & (TT - 1)) + seg * 16;
  uint4 v0 = *(uint4*)(tile + d * 72 + seg * 16);
  uint4 v1 = *(uint4*)(tile + d * 72 + seg * 16 + 8);
  uint4* dst = (uint4*)(xt + ((size_t)b * DD + d) * TT + tcol);
  dst[0] = v0;
  dst[1] = v1;
}

// ---------- kb: mm_j = m_j + ln( sum_k exp(x_j.x_k - m_j) ) ----------
// block = 32 j-rows; 4 waves each sweep a private k-quarter; per-wave
// double-buffered LDS slab with explicit vmcnt pipeline (no in-loop barrier).
__global__ __launch_bounds__(256) void kb_l(const unsigned short* __restrict__ xq,
                                            const float* __restrict__ m,
                                            float* __restrict__ mm) {
  __shared__ __align__(16) unsigned short kslab[4][2][2048];
  __shared__ float lpart[4][32];
  int w = threadIdx.x >> 6, lane = threadIdx.x & 63;
  int c = lane & 15, q = lane >> 4;
  int lid = blockIdx.x;
  int b = (lid >> 2) & 1;
  int tile = (lid & 3) | ((lid >> 3) << 2);  // 0..255
  int j0g = b * TT + tile * 32;
  bf16x8 a0[2], a1[2];
  f32x4 mv[2];
#pragma unroll
  for (int u = 0; u < 2; ++u) {
    const unsigned short* pr = xq + (size_t)(j0g + u * 16 + c) * DD + q * 8;
    a0[u] = *(const bf16x8*)pr;
    a1[u] = *(const bf16x8*)(pr + 32);
    mv[u] = *(const f32x4*)(m + j0g + u * 16 + 4 * q);
  }
  const unsigned short* xqb = xq + (size_t)(b * TT) * DD;
  int k0 = w * 2048;
  int srow = lane >> 3;
  int sch = (lane & 7) ^ srow;
  unsigned short* sb = &kslab[w][0][0];
  auto stage = [&](int buf, int kbase) {
#pragma unroll
    for (int t = 0; t < 4; ++t)
      gld_lds16(xqb + (size_t)(kbase + t * 8 + srow) * DD + sch * 8,
                sb + buf * 2048 + t * 512);
  };
  stage(0, k0);
  float ls[2][4] = {{0.f, 0.f, 0.f, 0.f}, {0.f, 0.f, 0.f, 0.f}};
  int o1 = (q ^ (c & 7)) * 8, o2 = ((q | 4) ^ (c & 7)) * 8;
  for (int it = 0; it < 64; ++it) {
    if (it < 63) {
      stage((it & 1) ^ 1, k0 + (it + 1) * 32);
      __builtin_amdgcn_s_waitcnt(0xF74);  // leave 4 prefetch loads in flight
    } else {
      __builtin_amdgcn_s_waitcnt(0xF70);
    }
    __builtin_amdgcn_sched_barrier(0);
    const unsigned short* kp = sb + (it & 1) * 2048;
    bf16x8 b00 = *(const bf16x8*)(kp + c * 64 + o1);
    bf16x8 b01 = *(const bf16x8*)(kp + c * 64 + o2);
    bf16x8 b10 = *(const bf16x8*)(kp + (c + 16) * 64 + o1);
    bf16x8 b11 = *(const bf16x8*)(kp + (c + 16) * 64 + o2);
#pragma unroll
    for (int u = 0; u < 2; ++u) {
      f32x4 z = {0.f, 0.f, 0.f, 0.f};
      f32x4 acc0 = MFMA16(a0[u], b00, z, 0, 0, 0);
      acc0 = MFMA16(a1[u], b01, acc0, 0, 0, 0);
      f32x4 acc1 = MFMA16(a0[u], b10, z, 0, 0, 0);
      acc1 = MFMA16(a1[u], b11, acc1, 0, 0, 0);
#pragma unroll
      for (int e = 0; e < 4; ++e)
        ls[u][e] += __expf(acc0[e] - mv[u][e]) + __expf(acc1[e] - mv[u][e]);
    }
  }
#pragma unroll
  for (int u = 0; u < 2; ++u)
#pragma unroll
    for (int e = 0; e < 4; ++e) {
      float v = ls[u][e];
      v += __shfl_xor(v, 1, 64);
      v += __shfl_xor(v, 2, 64);
      v += __shfl_xor(v, 4, 64);
      v += __shfl_xor(v, 8, 64);
      if (c == 0) lpart[w][u * 16 + 4 * q + e] = v;
    }
  __syncthreads();
  int t = threadIdx.x;
  if (t < 32) {
    float s = lpart[0][t] + lpart[1][t] + lpart[2][t] + lpart[3][t];
    mm[j0g + t] = m[j0g + t] + __logf(s);
  }
}

// ---------- kc: out[b][d][i] = sum_j exp(x_j.x_i - mm_j) * x_j[d] ----------
// block = 32-i tile; 4 waves sweep private j-quarters with explicit vmcnt
// pipeline (no in-loop barrier); P C->A transform via verified shfl path;
// O reduced across waves in LDS; plain (non-atomic) stores.
__global__ __launch_bounds__(256) void kc_out(const unsigned short* __restrict__ xq,
                                              const unsigned short* __restrict__ xt,
                                              const float* __restrict__ mm,
                                              float* __restrict__ out) {
  __shared__ __align__(16) unsigned short smem[36864];  // A 16384 | V 16384 | (epilogue overlay)
  int w = threadIdx.x >> 6, lane = threadIdx.x & 63;
  int c = lane & 15, q = lane >> 4;
  int lid = blockIdx.x;
  int b = (lid >> 2) & 1;
  int tile = (lid & 3) | ((lid >> 3) << 2);
  int i0 = tile * 32;
  bf16x8 bq0[2], bq1[2];
#pragma unroll
  for (int u = 0; u < 2; ++u) {
    const unsigned short* pr = xq + (size_t)(b * TT + i0 + u * 16 + c) * DD + q * 8;
    bq0[u] = *(const bf16x8*)pr;
    bq1[u] = *(const bf16x8*)(pr + 32);
  }
  f32x4 o[2][4];
#pragma unroll
  for (int u = 0; u < 2; ++u)
#pragma unroll
    for (int nt = 0; nt < 4; ++nt) o[u][nt] = (f32x4){0.f, 0.f, 0.f, 0.f};

  const unsigned short* xqb = xq + (size_t)(b * TT) * DD;
  const unsigned short* xtb = xt + (size_t)b * DD * TT;
  const float* mmb = mm + b * TT;
  int jq0 = w * 2048;
  unsigned short* asb = smem + w * 4096;
  unsigned short* vsb = smem + 16384 + w * 4096;
  int srow = lane >> 3;
  int sch = (lane & 7) ^ srow;
  int vr = lane >> 2;
  int vch = (lane & 3) ^ (vr & 3) ^ ((lane >> 4) & 3);
  auto stage = [&](int buf, int j) {
#pragma unroll
    for (int t = 0; t < 4; ++t)
      gld_lds16(xqb + (size_t)(j + t * 8 + srow) * DD + sch * 8,
                asb + buf * 2048 + t * 512);
#pragma unroll
    for (int t = 0; t < 4; ++t)
      gld_lds16(xtb + (size_t)(t * 16 + vr) * TT + j + vch * 8,
                vsb + buf * 2048 + t * 512);
  };
  stage(0, jq0);
  f32x4 mm0 = *(const f32x4*)(mmb + jq0 + 4 * q);
  f32x4 mm1 = *(const f32x4*)(mmb + jq0 + 16 + 4 * q);

  int o1 = (q ^ (c & 7)) * 8, o2 = ((q | 4) ^ (c & 7)) * 8;
  int swc = (c & 3) ^ ((c >> 2) & 3);
  int vo = (q ^ swc) * 8;
  int src0 = c + 32 * (q & 1);
  int src1 = src0 + 16;
  bool useT1 = (q >= 2);

  for (int it = 0; it < 64; ++it) {
    int jc = jq0 + it * 32;
    f32x4 mmn0 = mm0, mmn1 = mm1;
    if (it < 63) {
      stage((it & 1) ^ 1, jc + 32);
      mmn0 = *(const f32x4*)(mmb + jc + 32 + 4 * q);
      mmn1 = *(const f32x4*)(mmb + jc + 48 + 4 * q);
      __builtin_amdgcn_s_waitcnt(0xF7A);  // leave 8 DMA + 2 mm loads in flight
    } else {
      __builtin_amdgcn_s_waitcnt(0xF70);
    }
    __builtin_amdgcn_sched_barrier(0);
    const unsigned short* ap = asb + (it & 1) * 2048;
    const unsigned short* vp = vsb + (it & 1) * 2048;
    bf16x8 a00 = *(const bf16x8*)(ap + c * 64 + o1);
    bf16x8 a01 = *(const bf16x8*)(ap + c * 64 + o2);
    bf16x8 a10 = *(const bf16x8*)(ap + (c + 16) * 64 + o1);
    bf16x8 a11 = *(const bf16x8*)(ap + (c + 16) * 64 + o2);
    bf16x8 bv0 = *(const bf16x8*)(vp + (0 * 16 + c) * 32 + vo);
    bf16x8 bv1 = *(const bf16x8*)(vp + (1 * 16 + c) * 32 + vo);
    bf16x8 bv2 = *(const bf16x8*)(vp + (2 * 16 + c) * 32 + vo);
    bf16x8 bv3 = *(const bf16x8*)(vp + (3 * 16 + c) * 32 + vo);
#pragma unroll
    for (int u = 0; u < 2; ++u) {
      f32x4 z = {0.f, 0.f, 0.f, 0.f};
      f32x4 s0 = MFMA16(a00, bq0[u], z, 0, 0, 0);
      s0 = MFMA16(a01, bq1[u], s0, 0, 0, 0);
      f32x4 s1 = MFMA16(a10, bq0[u], z, 0, 0, 0);
      s1 = MFMA16(a11, bq1[u], s1, 0, 0, 0);
      float w00 = __expf(s0[0] - mm0[0]);
      float w01 = __expf(s0[1] - mm0[1]);
      float w02 = __expf(s0[2] - mm0[2]);
      float w03 = __expf(s0[3] - mm0[3]);
      float w10 = __expf(s1[0] - mm1[0]);
      float w11 = __expf(s1[1] - mm1[1]);
      float w12 = __expf(s1[2] - mm1[2]);
      float w13 = __expf(s1[3] - mm1[3]);
      unsigned int pk00 = pk2bf(w00, w01), pk01 = pk2bf(w02, w03);
      unsigned int pk10 = pk2bf(w10, w11), pk11 = pk2bf(w12, w13);
      unsigned int g00 = (unsigned int)__shfl((int)pk00, src0, 64);
      unsigned int g01 = (unsigned int)__shfl((int)pk01, src0, 64);
      unsigned int g10 = (unsigned int)__shfl((int)pk10, src0, 64);
      unsigned int g11 = (unsigned int)__shfl((int)pk11, src0, 64);
      unsigned int h00 = (unsigned int)__shfl((int)pk00, src1, 64);
      unsigned int h01 = (unsigned int)__shfl((int)pk01, src1, 64);
      unsigned int h10 = (unsigned int)__shfl((int)pk10, src1, 64);
      unsigned int h11 = (unsigned int)__shfl((int)pk11, src1, 64);
      union { unsigned int u[4]; bf16x8 v; } apv;
      apv.u[0] = useT1 ? g10 : g00;
      apv.u[1] = useT1 ? g11 : g01;
      apv.u[2] = useT1 ? h10 : h00;
      apv.u[3] = useT1 ? h11 : h01;
      o[u][0] = MFMA16(apv.v, bv0, o[u][0], 0, 0, 0);
      o[u][1] = MFMA16(apv.v, bv1, o[u][1], 0, 0, 0);
      o[u][2] = MFMA16(apv.v, bv2, o[u][2], 0, 0, 0);
      o[u][3] = MFMA16(apv.v, bv3, o[u][3], 0, 0, 0);
    }
    mm0 = mmn0;
    mm1 = mmn1;
  }
  // cross-wave O reduce: Olds[w][d 64][pitch 36 fp32], overlays A+V region
  __syncthreads();
  float* ow = (float*)smem + w * 2304;
#pragma unroll
  for (int u = 0; u < 2; ++u)
#pragma unroll
    for (int nt = 0; nt < 4; ++nt)
      *(f32x4*)(ow + (nt * 16 + c) * 36 + u * 16 + 4 * q) = o[u][nt];
  __syncthreads();
  int t = threadIdx.x, d = t & 63, g = t >> 6;
  const float* sbase = (const float*)smem;
  f32x4 sA = {0.f, 0.f, 0.f, 0.f}, sB = {0.f, 0.f, 0.f, 0.f};
#pragma unroll
  for (int w2 = 0; w2 < 4; ++w2) {
    const float* p = sbase + w2 * 2304 + d * 36 + g * 8;
    sA += *(const f32x4*)p;
    sB += *(const f32x4*)(p + 4);
  }
  float* ob = out + ((size_t)(b * DD + d)) * TT + i0 + g * 8;
  *(f32x4*)ob = sA;
  *(f32x4*)(ob + 4) = sB;
}

extern "C" void kernel_launch(void* const* d_in, const int* in_sizes, int n_in,
                              void* d_out, int out_size, void* d_ws, size_t ws_size,
                              hipStream_t stream) {
  const float* x = (const float*)d_in[0];
  float* out = (float*)d_out;
  unsigned short* xb = (unsigned short*)d_ws;
  unsigned short* xt = xb + (size_t)NROWS * DD;
  float* m = (float*)(xt + (size_t)NROWS * DD);
  float* mmv = m + NROWS;

  ka_init<<<NROWS / 64, 256, 0, stream>>>(x, xb, xt, m);
  kb_l<<<512, 256, 0, stream>>>(xb, m, mmv);
  kc_out<<<512, 256, 0, stream>>>(xb, xt, mmv, out);
}